// Round 4
// baseline (721.483 us; speedup 1.0000x reference)
//
#include <hip/hip_runtime.h>

typedef __attribute__((ext_vector_type(8))) short short8;   // 8 bf16 (MFMA A/B frag)
typedef __attribute__((ext_vector_type(4))) float f32x4;    // MFMA C/D frag

#define MFMA16(a, b, c) __builtin_amdgcn_mfma_f32_16x16x32_bf16((a), (b), (c), 0, 0, 0)

// fp32 -> bf16 RNE
static __device__ inline short f2bf(float x) {
    union { float f; unsigned u; } v;
    v.f = x;
    unsigned r = v.u + 0x7fffu + ((v.u >> 16) & 1u);
    return (short)(r >> 16);
}

// B=512, E=4, N=256, F=64
// out[b,n,g] = sum_e adj[b,e] @ (node[b] @ W_e + b_e) + node[b] @ W_add + b_add
//
// Direct-from-global adj design: the A-fragment of the adj@hidden MFMA is,
// per lane, 8 CONSECUTIVE floats of one adj row -> load it straight from
// global as 2x float4 and convert in-register. No adjL LDS buffer, no
// ds_write of adj, and (critically) NO barriers in the hot loop, so global
// loads pipeline freely across MFMA (no vmcnt(0)-at-barrier drain, which
// killed the staged versions). Each adj byte is fetched exactly once,
// 128 B-segment coalesced per wave.
__global__ __launch_bounds__(256, 2) void gconv_kernel(
    const float* __restrict__ node,    // [512,256,64]
    const float* __restrict__ adj,     // [512,4,256,256]
    const float* __restrict__ W_edge,  // [4,64,64]
    const float* __restrict__ b_edge,  // [4,64]
    const float* __restrict__ W_add,   // [64,64]
    const float* __restrict__ b_add,   // [64]
    float* __restrict__ out)           // [512,256,64]
{
    // hiddenT row stride 264 shorts = 132 dwords (== 4 mod 32): 16-lane frag
    // reads land 2 lanes/bank-quad = free 2-way alias.
    __shared__ short hiddenT[64][264];   // hidden_e^T [g][m]  33792 B
    __shared__ short wT[64][72];         // weight^T [g][f]     9216 B
                                         // total 43008 B
    const int b    = blockIdx.x;
    const int t    = threadIdx.x;
    const int lane = t & 63;
    const int w    = t >> 6;        // wave 0..3
    const int col  = lane & 15;     // A-row / B-col / D-col within 16-tile
    const int kq   = lane >> 4;     // k-offset 8*kq; D-rows 4*kq..4*kq+3

    const float* nodeB = node + (size_t)b * (256 * 64);
    const float* adjB  = adj  + (size_t)b * (4 * 256 * 256);

    // ---- node[b] A-fragments -> registers (rows st*64+16w+col) ----
    short8 anode[4][2];
    #pragma unroll
    for (int st = 0; st < 4; ++st)
        #pragma unroll
        for (int h = 0; h < 2; ++h) {
            const float* p = nodeB + (st * 64 + 16 * w + col) * 64 + 32 * h + 8 * kq;
            float4 v0 = *(const float4*)p;
            float4 v1 = *(const float4*)(p + 4);
            short8 a;
            a[0] = f2bf(v0.x); a[1] = f2bf(v0.y); a[2] = f2bf(v0.z); a[3] = f2bf(v0.w);
            a[4] = f2bf(v1.x); a[5] = f2bf(v1.y); a[6] = f2bf(v1.z); a[7] = f2bf(v1.w);
            anode[st][h] = a;
        }

    // ---- stage W_add^T -> wT ----
    #pragma unroll
    for (int i = 0; i < 16; ++i) {
        int idx = i * 256 + t;
        wT[idx & 63][idx >> 6] = f2bf(W_add[idx]);
    }
    __syncthreads();

    // ---- residual: acc[st][ct] = node_rows(st) @ W_add ----
    f32x4 acc[4][4];
    {
        const f32x4 zf = {0.f, 0.f, 0.f, 0.f};
        #pragma unroll
        for (int st = 0; st < 4; ++st)
            #pragma unroll
            for (int ct = 0; ct < 4; ++ct)
                acc[st][ct] = zf;
        #pragma unroll
        for (int h = 0; h < 2; ++h) {
            short8 bfr[4];
            #pragma unroll
            for (int ct = 0; ct < 4; ++ct)
                bfr[ct] = *(const short8*)&wT[16 * ct + col][32 * h + 8 * kq];
            #pragma unroll
            for (int st = 0; st < 4; ++st)
                #pragma unroll
                for (int ct = 0; ct < 4; ++ct)
                    acc[st][ct] = MFMA16(anode[st][h], bfr[ct], acc[st][ct]);
        }
    }
    __syncthreads();    // wT reads done before e-loop restage

    #pragma unroll 1
    for (int e = 0; e < 4; ++e) {
        // ---- stage W_edge[e]^T -> wT ----
        const float* We = W_edge + e * (64 * 64);
        #pragma unroll
        for (int i = 0; i < 16; ++i) {
            int idx = i * 256 + t;
            wT[idx & 63][idx >> 6] = f2bf(We[idx]);
        }
        float bedge[4];
        #pragma unroll
        for (int ct = 0; ct < 4; ++ct)
            bedge[ct] = b_edge[e * 64 + 16 * ct + col];
        __syncthreads();    // wT staged; also orders prev-e hiddenT reads
                            // before this e's hiddenT writes

        // ---- hidden_e = node @ W_e + b_e  -> hiddenT[g][m] bf16 (all 256 m) ----
        #pragma unroll
        for (int ct = 0; ct < 4; ++ct) {
            short8 b0 = *(const short8*)&wT[16 * ct + col][8 * kq];
            short8 b1 = *(const short8*)&wT[16 * ct + col][32 + 8 * kq];
            #pragma unroll
            for (int st = 0; st < 4; ++st) {
                f32x4 h = {0.f, 0.f, 0.f, 0.f};
                h = MFMA16(anode[st][0], b0, h);
                h = MFMA16(anode[st][1], b1, h);
                short4 s;
                s.x = f2bf(h[0] + bedge[ct]); s.y = f2bf(h[1] + bedge[ct]);
                s.z = f2bf(h[2] + bedge[ct]); s.w = f2bf(h[3] + bedge[ct]);
                *(short4*)&hiddenT[16 * ct + col][st * 64 + 16 * w + 4 * kq] = s;
            }
        }
        __syncthreads();

        // ---- acc[mt][·] += adj[b,e] @ hidden_e, K=256, adj direct from global ----
        // lane fragment: rows mt*64+16w+col, cols 32ks+8kq..+7; per-wave each
        // load instr covers 16 rows x 32 B; v0+v1 together span 128 B-aligned
        // segments -> full line use, each byte fetched once.
        const float* aRow = adjB + e * (256 * 256) + (16 * w + col) * 256 + 8 * kq;
        #pragma unroll
        for (int mt = 0; mt < 4; ++mt) {
            const float* ap = aRow + mt * (64 * 256);
            #pragma unroll 2
            for (int ks = 0; ks < 8; ++ks) {
                float4 v0 = *(const float4*)(ap + 32 * ks);
                float4 v1 = *(const float4*)(ap + 32 * ks + 4);
                short8 af;
                af[0] = f2bf(v0.x); af[1] = f2bf(v0.y);
                af[2] = f2bf(v0.z); af[3] = f2bf(v0.w);
                af[4] = f2bf(v1.x); af[5] = f2bf(v1.y);
                af[6] = f2bf(v1.z); af[7] = f2bf(v1.w);
                #pragma unroll
                for (int ct = 0; ct < 4; ++ct) {
                    short8 bf = *(const short8*)&hiddenT[16 * ct + col][32 * ks + 8 * kq];
                    acc[mt][ct] = MFMA16(af, bf, acc[mt][ct]);
                }
            }
        }
        // no trailing barrier: each wave's hiddenT ds_reads retire before it
        // passes the next iteration's post-wT-stage barrier
    }

    // ---- epilogue: out = acc + b_add ----
    float* outB = out + (size_t)b * (256 * 64);
    #pragma unroll
    for (int ct = 0; ct < 4; ++ct) {
        float bias = b_add[16 * ct + col];
        #pragma unroll
        for (int st = 0; st < 4; ++st) {
            int row = st * 64 + 16 * w + 4 * kq;
            #pragma unroll
            for (int r = 0; r < 4; ++r)
                outB[(size_t)(row + r) * 64 + 16 * ct + col] = acc[st][ct][r] + bias;
        }
    }
}

extern "C" void kernel_launch(void* const* d_in, const int* in_sizes, int n_in,
                              void* d_out, int out_size, void* d_ws, size_t ws_size,
                              hipStream_t stream) {
    const float* node   = (const float*)d_in[0];
    const float* adj    = (const float*)d_in[1];
    const float* W_edge = (const float*)d_in[2];
    const float* b_edge = (const float*)d_in[3];
    const float* W_add  = (const float*)d_in[4];
    const float* b_add  = (const float*)d_in[5];
    float* out = (float*)d_out;

    gconv_kernel<<<dim3(512), dim3(256), 0, stream>>>(
        node, adj, W_edge, b_edge, W_add, b_add, out);
}